// Round 12
// baseline (9777.348 us; speedup 1.0000x reference)
//
#include <hip/hip_runtime.h>

#define T_LEN 4096
#define EMB   300
#define HD    256
#define G4    1024      // 4*HD (gate rows per direction)
#define N2    2048      // both directions
#define TAGS  12
#define NEGV  -10000.0f
#define SENT  0x7F7F7F7Fu   // memset byte 0x7F -> 3.396e38f; |partial|<=16 so never produced
#define NSLOT 16

// ---------------------------------------------------------------------------
// Kernel 1: g_in[t][dir*1024 + r] = embed[sent[t]] . W_ih_dir[r] + b_ih + b_hh
// 64x64 tiles, 256 thr, 4x4 acc, transposed LDS staging.
// ---------------------------------------------------------------------------
__global__ __launch_bounds__(256) void gin_gemm(
    const int* __restrict__ sent, const float* __restrict__ embed,
    const float* __restrict__ Wf, const float* __restrict__ Wb,
    const float* __restrict__ bihf, const float* __restrict__ bhhf,
    const float* __restrict__ bihb, const float* __restrict__ bhhb,
    float* __restrict__ gin)
{
    __shared__ float AsT[32][68];
    __shared__ float BsT[32][68];
    __shared__ int   sIdx[64];
    const int tid = threadIdx.x;
    const int bn = blockIdx.x;   // 0..31  (N tiles over 2048)
    const int bm = blockIdx.y;   // 0..63  (M tiles over 4096)
    if (tid < 64) sIdx[tid] = sent[bm*64 + tid];
    __syncthreads();

    float acc[4][4] = {};
    const int lr = tid >> 3;          // 0..31
    const int lk = (tid & 7) << 2;    // 0,4,..,28
    const int m0 = (tid >> 4) << 2;
    const int n0 = (tid & 15) << 2;

    for (int kc = 0; kc < 10; ++kc) {           // K chunks of 32 (covers 320, guard 300)
        const int k0 = kc*32 + lk;
        #pragma unroll
        for (int h = 0; h < 2; ++h) {
            const int row = lr + h*32;
            float4 va = make_float4(0.f,0.f,0.f,0.f);
            if (k0 + 3 < EMB)   // EMB % 4 == 0: vectors are all-or-nothing
                va = *(const float4*)(embed + (long)sIdx[row]*EMB + k0);
            AsT[lk+0][row]=va.x; AsT[lk+1][row]=va.y;
            AsT[lk+2][row]=va.z; AsT[lk+3][row]=va.w;

            const int rn = bn*64 + row;          // tiles never straddle the 1024 split
            const float* bsrc = (rn < G4) ? (Wf + (long)rn*EMB) : (Wb + (long)(rn-G4)*EMB);
            float4 vb = make_float4(0.f,0.f,0.f,0.f);
            if (k0 + 3 < EMB)
                vb = *(const float4*)(bsrc + k0);
            BsT[lk+0][row]=vb.x; BsT[lk+1][row]=vb.y;
            BsT[lk+2][row]=vb.z; BsT[lk+3][row]=vb.w;
        }
        __syncthreads();
        #pragma unroll
        for (int kk = 0; kk < 32; ++kk) {
            const float4 a4 = *(const float4*)&AsT[kk][m0];
            const float4 b4 = *(const float4*)&BsT[kk][n0];
            const float a[4] = {a4.x, a4.y, a4.z, a4.w};
            const float b[4] = {b4.x, b4.y, b4.z, b4.w};
            #pragma unroll
            for (int i = 0; i < 4; ++i)
                #pragma unroll
                for (int jj = 0; jj < 4; ++jj)
                    acc[i][jj] = fmaf(a[i], b[jj], acc[i][jj]);
        }
        __syncthreads();
    }

    #pragma unroll
    for (int i = 0; i < 4; ++i) {
        const int t = bm*64 + m0 + i;
        #pragma unroll
        for (int jj = 0; jj < 4; ++jj) {
            const int r = bn*64 + n0 + jj;
            const float bias = (r < G4) ? (bihf[r] + bhhf[r])
                                        : (bihb[r-G4] + bhhb[r-G4]);
            gin[(long)t*N2 + r] = acc[i][jj] + bias;
        }
    }
}

// ---------------------------------------------------------------------------
// Kernel 2: persistent BiLSTM — PARTIAL-SUM exchange, 4 blocks x 1024/dir.
// Thread r (0..1023) owns full gate row r over the block's 64-COLUMN slice:
// partial[r] = W[r, 64b..64b+63] . h[64b..64b+63], h fully LOCAL (every
// block redundantly computes all 256 c/h each step — bitwise identical since
// all blocks sum the same 4 partials in the same positional order).
// Exchange = the 4 partial vectors via a 16-slot ring in global memory:
// relaxed agent-scope store (NO release — r6 lesson), poll 3 foreign words
// per thread (data-is-flag), producer sentinel-prefills its slot for s+8
// (reuse margin ~8 steps). Matvec + weight loads sit BEFORE the publish, so
// exchange latency no longer stacks on top of them.
// ---------------------------------------------------------------------------
#define MV(K) { const float4 hv = h4[K];                    \
    a0 = fmaf(wA##K.x, hv.x, a0);                           \
    a1 = fmaf(wA##K.y, hv.y, a1);                           \
    a2 = fmaf(wA##K.z, hv.z, a2);                           \
    a3 = fmaf(wA##K.w, hv.w, a3); }

__global__ __launch_bounds__(1024, 4)
void lstm_persist(
    const float* __restrict__ Whh_f, const float* __restrict__ Whh_b,
    const float* __restrict__ h0, const float* __restrict__ c0,
    const float* __restrict__ gin,
    float* __restrict__ Hh,          // [T][512] history (plain stores, block 0 only)
    float* __restrict__ Pbuf)        // [NSLOT][2][4][1024] partials, 0x7F-filled
{
    const int blk = blockIdx.x;
    const int m8  = blk & 7;
    if (m8 != 0 && m8 != 4) return;     // XCD placement spacers
    const int dir = (m8 == 4);
    const int b   = blk >> 3;           // column-slice 0..3
    const int tid = threadIdx.x;        // = gate row r, 0..1023
    const int gate = tid >> 8;

    // --- 64 weights (row r, column slice b) as named SSA float4 ---
    const float4* W4 = (const float4*)((dir ? Whh_b : Whh_f)
                                       + (long)tid*HD + b*64);
    const float4 wA0  = W4[0],  wA1  = W4[1],  wA2  = W4[2],  wA3  = W4[3];
    const float4 wA4  = W4[4],  wA5  = W4[5],  wA6  = W4[6],  wA7  = W4[7];
    const float4 wA8  = W4[8],  wA9  = W4[9],  wA10 = W4[10], wA11 = W4[11];
    const float4 wA12 = W4[12], wA13 = W4[13], wA14 = W4[14], wA15 = W4[15];

    // 80 KB hS (only [0..255] used): LDS-forces 1 block/CU.
    __shared__ __align__(16) float hS[20480];
    __shared__ float gvS[G4];

    float cst = 0.f;
    if (tid < HD) {
        cst = c0[dir*HD + tid];
        hS[tid] = h0[dir*HD + tid];
    }
    __syncthreads();

    const float* ginD = gin + dir*G4;
    float gx = ginD[(long)(dir ? T_LEN-1 : 0)*N2 + tid];

    // the 3 foreign block ids, ascending
    const int f0 = (b == 0) ? 1 : 0;
    const int f1 = (b <= 1) ? 2 : 1;
    const int f2 = (b <= 2) ? 3 : 2;

    #pragma unroll 1
    for (int s = 0; s < T_LEN; ++s) {
        const int t = dir ? (T_LEN-1-s) : s;
        float gxn = 0.f;
        if (s+1 < T_LEN)                       // prefetch next step's gin
            gxn = ginD[(long)(dir ? t-1 : t+1)*N2 + tid];

        // ---- local matvec over own 64 columns (h is fully local) ----
        const float4* h4 = (const float4*)(hS + b*64);
        float a0=0.f, a1=0.f, a2=0.f, a3=0.f;
        MV(0)  MV(1)  MV(2)  MV(3)
        MV(4)  MV(5)  MV(6)  MV(7)
        MV(8)  MV(9)  MV(10) MV(11)
        MV(12) MV(13) MV(14) MV(15)
        const float a = (a0+a1)+(a2+a3);

        // ---- publish partial + sentinel-prefill own slot for s+8 ----
        const long sb  = ((long)((s & (NSLOT-1))*2 + dir))*4096;
        const long sbf = ((long)((((s+8) & (NSLOT-1))*2) + dir))*4096;
        __hip_atomic_store(&Pbuf[sb  + b*1024 + tid], a,
                           __ATOMIC_RELAXED, __HIP_MEMORY_SCOPE_AGENT);
        __hip_atomic_store(&Pbuf[sbf + b*1024 + tid], __uint_as_float(SENT),
                           __ATOMIC_RELAXED, __HIP_MEMORY_SCOPE_AGENT);

        // ---- poll the 3 foreign partials (one-hop, data is the flag) ----
        float* P0 = Pbuf + sb + f0*1024 + tid;
        float* P1 = Pbuf + sb + f1*1024 + tid;
        float* P2 = Pbuf + sb + f2*1024 + tid;
        float v0 = 0.f, v1 = 0.f, v2 = 0.f;
        bool d0 = false, d1 = false, d2 = false;
        do {
            if (!d0) { v0 = __hip_atomic_load(P0, __ATOMIC_RELAXED,
                                              __HIP_MEMORY_SCOPE_AGENT);
                       d0 = (__float_as_uint(v0) != SENT); }
            if (!d1) { v1 = __hip_atomic_load(P1, __ATOMIC_RELAXED,
                                              __HIP_MEMORY_SCOPE_AGENT);
                       d1 = (__float_as_uint(v1) != SENT); }
            if (!d2) { v2 = __hip_atomic_load(P2, __ATOMIC_RELAXED,
                                              __HIP_MEMORY_SCOPE_AGENT);
                       d2 = (__float_as_uint(v2) != SENT); }
        } while (!(d0 && d1 && d2));

        // ---- positional sum (identical order in every block) + activate ----
        const float pos0 = (b == 0) ? a : v0;
        const float pos1 = (b == 1) ? a : ((b == 0) ? v0 : v1);
        const float pos2 = (b == 2) ? a : ((b <= 1) ? v1 : v2);
        const float pos3 = (b == 3) ? a : v2;
        const float g = ((pos0 + pos1) + (pos2 + pos3)) + gx;
        gvS[tid] = (gate == 2) ? tanhf(g) : 1.f/(1.f + expf(-g));
        __syncthreads();                       // (B) gvS complete

        if (tid < HD) {                        // every block: full c/h update
            const float i_ = gvS[tid],        f_ = gvS[HD + tid];
            const float g_ = gvS[2*HD + tid], o_ = gvS[3*HD + tid];
            cst = fmaf(f_, cst, i_*g_);
            const float hv = o_ * tanhf(cst);
            hS[tid] = hv;
            if (b == 0)                        // one block publishes history
                Hh[(long)t*512 + dir*HD + tid] = hv;
        }
        __syncthreads();                       // (C) hS ready for next step
        gx = gxn;
    }
}

// ---------------------------------------------------------------------------
// Kernel 3: feats[t][tag] = [hf|hb][t] . W_tag[tag] + b_tag
// ---------------------------------------------------------------------------
__global__ __launch_bounds__(192) void feats_kernel(
    const float* __restrict__ Hhist, const float* __restrict__ Wtag,
    const float* __restrict__ btag, float* __restrict__ feats)
{
    __shared__ __align__(16) float Ws[TAGS][512];
    const int tid = threadIdx.x;
    for (int i = tid; i < TAGS*512; i += 192) Ws[0][i] = Wtag[i];
    __syncthreads();
    const int tl = tid / TAGS;            // 0..15
    const int tg = tid % TAGS;
    const int t  = blockIdx.x * 16 + tl;
    const float4* hrow = (const float4*)(Hhist + (long)t*512);
    const float4* wrow = (const float4*)(&Ws[tg][0]);
    float a0=0.f,a1=0.f,a2=0.f,a3=0.f;
    #pragma unroll 8
    for (int k = 0; k < 128; ++k) {
        const float4 h = hrow[k];
        const float4 ww = wrow[k];
        a0=fmaf(h.x,ww.x,a0); a1=fmaf(h.y,ww.y,a1);
        a2=fmaf(h.z,ww.z,a2); a3=fmaf(h.w,ww.w,a3);
    }
    feats[t*TAGS + tg] = ((a0+a1)+(a2+a3)) + btag[tg];
}

// ---------------------------------------------------------------------------
// Kernel 4: Viterbi forward scan (12 lanes) + serial backtrack.
// ---------------------------------------------------------------------------
__global__ __launch_bounds__(256) void viterbi_kernel(
    const float* __restrict__ feats, const float* __restrict__ trans,
    float* __restrict__ out)
{
    __shared__ float fS[256*TAGS];                 // 12 KB feats chunk
    __shared__ unsigned char bps[T_LEN*TAGS];      // 48 KB backpointers
    __shared__ float fvS[TAGS];
    const int tid = threadIdx.x;

    float tr[TAGS];
    float fv = NEGV;
    if (tid < TAGS) {
        #pragma unroll
        for (int f = 0; f < TAGS; ++f) tr[f] = trans[tid*TAGS + f];
        fv = (tid == 10) ? 0.f : NEGV;             // START = 10
    }

    for (int c = 0; c < T_LEN/256; ++c) {
        __syncthreads();
        for (int i = tid; i < 256*TAGS; i += 256) fS[i] = feats[c*256*TAGS + i];
        __syncthreads();
        if (tid < TAGS) {
            for (int s = 0; s < 256; ++s) {
                float best = -3.4e38f; int bp = 0;
                #pragma unroll
                for (int f = 0; f < TAGS; ++f) {
                    const float v = __shfl(fv, f, 64) + tr[f];
                    if (v > best) { best = v; bp = f; }   // strict > = np argmax semantics
                }
                bps[(c*256+s)*TAGS + tid] = (unsigned char)bp;
                fv = best + fS[s*TAGS + tid];
            }
        }
    }
    __syncthreads();
    if (tid < TAGS) fvS[tid] = fv + trans[11*TAGS + tid];  // STOP = 11
    __syncthreads();
    if (tid == 0) {
        float bestv = fvS[0]; int best = 0;
        #pragma unroll
        for (int g = 1; g < TAGS; ++g) if (fvS[g] > bestv) { bestv = fvS[g]; best = g; }
        out[0] = bestv;
        int cur = best;
        for (int t = T_LEN-1; t >= 0; --t) {
            out[1+t] = (float)cur;
            cur = bps[t*TAGS + cur];
        }
    }
}

// ---------------------------------------------------------------------------
// Host launch.  ws layout (floats):
//   gin   [4096*2048]        = 33.5 MB
//   Hh    [4096*512]         =  8.4 MB  (no init needed — plain stores)
//   feats [4096*12]          =  0.2 MB
//   Pbuf  [16*2*4*1024]      =  0.5 MB  (sentinel-filled each launch)
// ---------------------------------------------------------------------------
extern "C" void kernel_launch(void* const* d_in, const int* in_sizes, int n_in,
                              void* d_out, int out_size, void* d_ws, size_t ws_size,
                              hipStream_t stream)
{
    (void)in_sizes; (void)n_in; (void)out_size; (void)ws_size;
    const int*   sentence = (const int*)  d_in[0];
    const float* h0       = (const float*)d_in[1];
    const float* c0       = (const float*)d_in[2];
    const float* embed    = (const float*)d_in[3];
    const float* Wihf     = (const float*)d_in[4];
    const float* Whhf     = (const float*)d_in[5];
    const float* bihf     = (const float*)d_in[6];
    const float* bhhf     = (const float*)d_in[7];
    const float* Wihb     = (const float*)d_in[8];
    const float* Whhb     = (const float*)d_in[9];
    const float* bihb     = (const float*)d_in[10];
    const float* bhhb     = (const float*)d_in[11];
    const float* Wtag     = (const float*)d_in[12];
    const float* btag     = (const float*)d_in[13];
    const float* trans    = (const float*)d_in[14];
    float* out = (float*)d_out;

    float* gin   = (float*)d_ws;
    float* Hh    = gin   + (long)T_LEN*N2;
    float* feats = Hh    + (long)T_LEN*512;
    float* Pbuf  = feats + (long)T_LEN*TAGS;

    // sentinel-fill the partial-exchange ring
    hipMemsetAsync(Pbuf, 0x7F, (size_t)NSLOT*2*4*1024*sizeof(float), stream);

    dim3 ggrid(32, 64);
    gin_gemm<<<ggrid, 256, 0, stream>>>(sentence, embed, Wihf, Wihb,
                                        bihf, bhhf, bihb, bhhb, gin);
    lstm_persist<<<29, 1024, 0, stream>>>(Whhf, Whhb, h0, c0, gin, Hh, Pbuf);
    feats_kernel<<<T_LEN/16, 192, 0, stream>>>(Hh, Wtag, btag, feats);
    viterbi_kernel<<<1, 256, 0, stream>>>(feats, trans, out);
}

// Round 13
// 7332.314 us; speedup vs baseline: 1.3335x; 1.3335x over previous
//
#include <hip/hip_runtime.h>

#define T_LEN 4096
#define EMB   300
#define HD    256
#define G4    1024      // 4*HD (gate rows per direction)
#define N2    2048      // both directions
#define TAGS  12
#define NEGV  -10000.0f
#define SENT  0x7F7F7F7Fu   // memset byte 0x7F -> 3.396e38f; real values never reach it
#define NLSTM 29            // lstm sub-grid (8 workers + XCD spacers)

// ---------------------------------------------------------------------------
// Fused kernel: blocks 0..28 = persistent BiLSTM (r10 structure, 5.50 ms —
// quarter gate-rows, one-hop h sentinel exchange); blocks 29.. = the gin
// GEMM (64x64 tiles, 1024 thr, 2x2/thread), running CONCURRENTLY.
//  * gin is 0x7F-sentinel-filled; GEMM publishes with relaxed agent-scope
//    atomic stores; LSTM polls (issue-early / check-late so L3 latency
//    hides under the step).
//  * GEMM tile order is middle-out in t (0,63,1,62,...) -> first-needed
//    tiles (both sequence ends) complete first.
//  * 145 KB LDS union: 1 block/CU everywhere -> GEMM can never co-reside
//    with (and steal cycles from) an LSTM CU. Deadlock-free under any
//    dispatch order (GEMM depends on nothing).
// ---------------------------------------------------------------------------
#define MV(K) { const float4 hv = h4[K];                    \
    a0 = fmaf(wA##K.x, hv.x, a0);                           \
    a1 = fmaf(wA##K.y, hv.y, a1);                           \
    a2 = fmaf(wA##K.z, hv.z, a2);                           \
    a3 = fmaf(wA##K.w, hv.w, a3); }

__global__ __launch_bounds__(1024) void fused_gemm_lstm(
    const int* __restrict__ sent, const float* __restrict__ embed,
    const float* __restrict__ Wihf, const float* __restrict__ Wihb,
    const float* __restrict__ bihf, const float* __restrict__ bhhf,
    const float* __restrict__ bihb, const float* __restrict__ bhhb,
    const float* Whh_f, const float* Whh_b,            // NOT restrict (anti-remat)
    const float* __restrict__ h0, const float* __restrict__ c0,
    float* gin,                      // [T][2048], 0x7F-filled; gemm writes, lstm polls
    float* Hh)                       // [T][512],  0x7F-filled; h exchange + history
{
    __shared__ __align__(16) char smem[145*1024];
    const int blk = blockIdx.x;
    const int tid = threadIdx.x;

    if (blk >= NLSTM) {
        // ================= GEMM path =================
        float* AsT  = (float*)smem;              // [32][68]
        float* BsT  = (float*)(smem + 8704);     // [32][68]
        int*   sIdx = (int*)  (smem + 17408);    // [64]
        const int g  = blk - NLSTM;
        const int kk8 = g >> 5;                  // 0..63
        const int bn  = g & 31;
        const int bm  = (kk8 & 1) ? (63 - (kk8 >> 1)) : (kk8 >> 1);  // middle-out

        if (tid < 64) sIdx[tid] = sent[bm*64 + tid];
        __syncthreads();

        const int srow = tid >> 4;               // 0..63
        const int skj  = (tid & 15) << 1;        // 0,2,..,30
        const int m0   = (tid >> 5) << 1;        // 0..62 (row pair)
        const int n0   = (tid & 31) << 1;        // 0..62 (col pair)
        const int rn   = bn * 64;
        float acc00=0.f, acc01=0.f, acc10=0.f, acc11=0.f;

        for (int kc = 0; kc < 10; ++kc) {        // K chunks of 32 (guard 300)
            const int k0 = kc*32 + skj;
            float2 va = make_float2(0.f, 0.f), vb = make_float2(0.f, 0.f);
            if (k0 + 1 < EMB) {                  // EMB even: float2 all-or-nothing
                va = *(const float2*)(embed + (long)sIdx[srow]*EMB + k0);
                const int r = rn + srow;
                const float* bsrc = (r < G4) ? (Wihf + (long)r*EMB)
                                             : (Wihb + (long)(r-G4)*EMB);
                vb = *(const float2*)(bsrc + k0);
            }
            AsT[skj*68 + srow]     = va.x;
            AsT[(skj+1)*68 + srow] = va.y;
            BsT[skj*68 + srow]     = vb.x;
            BsT[(skj+1)*68 + srow] = vb.y;
            __syncthreads();
            #pragma unroll
            for (int kk = 0; kk < 32; ++kk) {
                const float2 a2v = *(const float2*)&AsT[kk*68 + m0];
                const float2 b2v = *(const float2*)&BsT[kk*68 + n0];
                acc00 = fmaf(a2v.x, b2v.x, acc00);
                acc01 = fmaf(a2v.x, b2v.y, acc01);
                acc10 = fmaf(a2v.y, b2v.x, acc10);
                acc11 = fmaf(a2v.y, b2v.y, acc11);
            }
            __syncthreads();
        }

        const int c0i = rn + n0, c1i = c0i + 1;
        const float bias0 = (c0i < G4) ? (bihf[c0i] + bhhf[c0i])
                                       : (bihb[c0i-G4] + bhhb[c0i-G4]);
        const float bias1 = (c1i < G4) ? (bihf[c1i] + bhhf[c1i])
                                       : (bihb[c1i-G4] + bhhb[c1i-G4]);
        const long t0 = (long)(bm*64 + m0), t1 = t0 + 1;
        __hip_atomic_store(&gin[t0*N2 + c0i], acc00 + bias0,
                           __ATOMIC_RELAXED, __HIP_MEMORY_SCOPE_AGENT);
        __hip_atomic_store(&gin[t0*N2 + c1i], acc01 + bias1,
                           __ATOMIC_RELAXED, __HIP_MEMORY_SCOPE_AGENT);
        __hip_atomic_store(&gin[t1*N2 + c0i], acc10 + bias0,
                           __ATOMIC_RELAXED, __HIP_MEMORY_SCOPE_AGENT);
        __hip_atomic_store(&gin[t1*N2 + c1i], acc11 + bias1,
                           __ATOMIC_RELAXED, __HIP_MEMORY_SCOPE_AGENT);
        return;
    }

    // ================= LSTM path (r10 structure) =================
    const int m8 = blk & 7;
    if (m8 != 0 && m8 != 4) return;     // XCD placement spacers
    const int dir = (m8 == 4);
    const int b   = blk >> 3;           // unit-slice 0..3
    const int u     = tid & 63;
    const int wvid  = tid >> 6;         // 0..15
    const int gate  = wvid >> 2;        // wave-uniform
    const int q     = wvid & 3;         // wave-uniform quarter
    const int unit0 = b*64;
    const int row   = gate*64 + u;            // block-local row 0..255
    const int grow  = gate*HD + unit0 + u;    // gate row 0..1023

    float* hS  = (float*)smem;            // 256 floats
    float* ps  = (float*)(smem + 1024);   // [3][256]
    float* gvS = (float*)(smem + 4096);   // 256 floats

    // --- 64 weights as named SSA float4 ---
    const float4* W4 = (const float4*)((dir ? Whh_b : Whh_f)
                                       + (long)grow*HD + q*64);
    const float4 wA0  = W4[0],  wA1  = W4[1],  wA2  = W4[2],  wA3  = W4[3];
    const float4 wA4  = W4[4],  wA5  = W4[5],  wA6  = W4[6],  wA7  = W4[7];
    const float4 wA8  = W4[8],  wA9  = W4[9],  wA10 = W4[10], wA11 = W4[11];
    const float4 wA12 = W4[12], wA13 = W4[13], wA14 = W4[14], wA15 = W4[15];

    float cst = 0.f;
    if (tid < 64) cst = c0[dir*HD + unit0 + tid];       // owners: wave 0
    if (tid < HD) hS[tid] = h0[dir*HD + tid];

    float* ginD = gin + dir*G4;
    float gx;
    {   // initial gin word: cold poll
        const long gi0 = (long)(dir ? T_LEN-1 : 0)*N2 + grow;
        do {
            gx = __hip_atomic_load(&ginD[gi0], __ATOMIC_RELAXED,
                                   __HIP_MEMORY_SCOPE_AGENT);
        } while (__float_as_uint(gx) == SENT);
    }

    #pragma unroll 1
    for (int s = 0; s < T_LEN; ++s) {
        const int t = dir ? (T_LEN-1-s) : s;
        float gxn = 0.f;
        long  gidx = 0;
        if (s+1 < T_LEN) {                     // issue next-step gin load EARLY
            gidx = (long)(dir ? t-1 : t+1)*N2 + grow;
            gxn = __hip_atomic_load(&ginD[gidx], __ATOMIC_RELAXED,
                                    __HIP_MEMORY_SCOPE_AGENT);
            __builtin_amdgcn_sched_barrier(0); // pin the early issue
        }

        __syncthreads();                       // (A) hS(s) complete
        const float4* h4 = (const float4*)(hS + q*64);   // uniform-addr broadcast
        float a0=0.f, a1=0.f, a2=0.f, a3=0.f;
        MV(0)  MV(1)  MV(2)  MV(3)
        MV(4)  MV(5)  MV(6)  MV(7)
        MV(8)  MV(9)  MV(10) MV(11)
        MV(12) MV(13) MV(14) MV(15)
        const float a = (a0+a1)+(a2+a3);
        if (q != 0) ps[(q-1)*256 + row] = a;
        __syncthreads();                       // (B) partials ready

        if (q == 0) {                          // waves 0,4,8,12: finalize + activate
            const float raw = a + ps[row] + ps[256+row] + ps[512+row] + gx;
            gvS[row] = (gate == 2) ? tanhf(raw) : 1.f/(1.f + expf(-raw));
        }
        __syncthreads();                       // (C) gvS ready

        if (tid < 64) {                        // wave 0 = owners: c/h update + publish
            const float i_ = gvS[tid],       f_ = gvS[64+tid];
            const float g_ = gvS[128+tid],   o_ = gvS[192+tid];
            cst = fmaf(f_, cst, i_*g_);
            const float hv = o_ * tanhf(cst);
            hS[unit0 + tid] = hv;              // own slice: LDS only
            __hip_atomic_store(&Hh[(long)t*512 + dir*HD + unit0 + tid], hv,
                               __ATOMIC_RELAXED, __HIP_MEMORY_SCOPE_AGENT);
        } else if (tid < 256 && s+1 < T_LEN) { // waves 1-3: poll one foreign word each
            const int fidx = tid - 64;                      // 0..191
            const int gu   = (fidx < unit0) ? fidx : fidx + 64;
            const long idx = (long)t*512 + dir*HD + gu;
            float v;
            do {
                v = __hip_atomic_load(&Hh[idx], __ATOMIC_RELAXED,
                                      __HIP_MEMORY_SCOPE_AGENT);
            } while (__float_as_uint(v) == SENT);
            hS[gu] = v;
        }

        if (s+1 < T_LEN) {                     // check-late: usually already ready
            while (__float_as_uint(gxn) == SENT)
                gxn = __hip_atomic_load(&ginD[gidx], __ATOMIC_RELAXED,
                                        __HIP_MEMORY_SCOPE_AGENT);
        }
        gx = gxn;
    }
}

// ---------------------------------------------------------------------------
// Kernel 3: feats[t][tag] = [hf|hb][t] . W_tag[tag] + b_tag
// ---------------------------------------------------------------------------
__global__ __launch_bounds__(192) void feats_kernel(
    const float* __restrict__ Hhist, const float* __restrict__ Wtag,
    const float* __restrict__ btag, float* __restrict__ feats)
{
    __shared__ __align__(16) float Ws[TAGS][512];
    const int tid = threadIdx.x;
    for (int i = tid; i < TAGS*512; i += 192) Ws[0][i] = Wtag[i];
    __syncthreads();
    const int tl = tid / TAGS;            // 0..15
    const int tg = tid % TAGS;
    const int t  = blockIdx.x * 16 + tl;
    const float4* hrow = (const float4*)(Hhist + (long)t*512);
    const float4* wrow = (const float4*)(&Ws[tg][0]);
    float a0=0.f,a1=0.f,a2=0.f,a3=0.f;
    #pragma unroll 8
    for (int k = 0; k < 128; ++k) {
        const float4 h = hrow[k];
        const float4 ww = wrow[k];
        a0=fmaf(h.x,ww.x,a0); a1=fmaf(h.y,ww.y,a1);
        a2=fmaf(h.z,ww.z,a2); a3=fmaf(h.w,ww.w,a3);
    }
    feats[t*TAGS + tg] = ((a0+a1)+(a2+a3)) + btag[tg];
}

// ---------------------------------------------------------------------------
// Kernel 4: Viterbi forward scan (12 lanes) + serial backtrack.
// ---------------------------------------------------------------------------
__global__ __launch_bounds__(256) void viterbi_kernel(
    const float* __restrict__ feats, const float* __restrict__ trans,
    float* __restrict__ out)
{
    __shared__ float fS[256*TAGS];                 // 12 KB feats chunk
    __shared__ unsigned char bps[T_LEN*TAGS];      // 48 KB backpointers
    __shared__ float fvS[TAGS];
    const int tid = threadIdx.x;

    float tr[TAGS];
    float fv = NEGV;
    if (tid < TAGS) {
        #pragma unroll
        for (int f = 0; f < TAGS; ++f) tr[f] = trans[tid*TAGS + f];
        fv = (tid == 10) ? 0.f : NEGV;             // START = 10
    }

    for (int c = 0; c < T_LEN/256; ++c) {
        __syncthreads();
        for (int i = tid; i < 256*TAGS; i += 256) fS[i] = feats[c*256*TAGS + i];
        __syncthreads();
        if (tid < TAGS) {
            for (int s = 0; s < 256; ++s) {
                float best = -3.4e38f; int bp = 0;
                #pragma unroll
                for (int f = 0; f < TAGS; ++f) {
                    const float v = __shfl(fv, f, 64) + tr[f];
                    if (v > best) { best = v; bp = f; }   // strict > = np argmax semantics
                }
                bps[(c*256+s)*TAGS + tid] = (unsigned char)bp;
                fv = best + fS[s*TAGS + tid];
            }
        }
    }
    __syncthreads();
    if (tid < TAGS) fvS[tid] = fv + trans[11*TAGS + tid];  // STOP = 11
    __syncthreads();
    if (tid == 0) {
        float bestv = fvS[0]; int best = 0;
        #pragma unroll
        for (int g = 1; g < TAGS; ++g) if (fvS[g] > bestv) { bestv = fvS[g]; best = g; }
        out[0] = bestv;
        int cur = best;
        for (int t = T_LEN-1; t >= 0; --t) {
            out[1+t] = (float)cur;
            cur = bps[t*TAGS + cur];
        }
    }
}

// ---------------------------------------------------------------------------
// Host launch.  ws layout (floats):
//   gin   [4096*2048] = 33.5 MB  (0x7F sentinel-filled each launch)
//   Hh    [4096*512]  =  8.4 MB  (0x7F sentinel-filled each launch)
//   feats [4096*12]   =  0.2 MB
// ---------------------------------------------------------------------------
extern "C" void kernel_launch(void* const* d_in, const int* in_sizes, int n_in,
                              void* d_out, int out_size, void* d_ws, size_t ws_size,
                              hipStream_t stream)
{
    (void)in_sizes; (void)n_in; (void)out_size; (void)ws_size;
    const int*   sentence = (const int*)  d_in[0];
    const float* h0       = (const float*)d_in[1];
    const float* c0       = (const float*)d_in[2];
    const float* embed    = (const float*)d_in[3];
    const float* Wihf     = (const float*)d_in[4];
    const float* Whhf     = (const float*)d_in[5];
    const float* bihf     = (const float*)d_in[6];
    const float* bhhf     = (const float*)d_in[7];
    const float* Wihb     = (const float*)d_in[8];
    const float* Whhb     = (const float*)d_in[9];
    const float* bihb     = (const float*)d_in[10];
    const float* bhhb     = (const float*)d_in[11];
    const float* Wtag     = (const float*)d_in[12];
    const float* btag     = (const float*)d_in[13];
    const float* trans    = (const float*)d_in[14];
    float* out = (float*)d_out;

    float* gin   = (float*)d_ws;
    float* Hh    = gin + (long)T_LEN*N2;
    float* feats = Hh  + (long)T_LEN*512;

    hipMemsetAsync(gin, 0x7F, (size_t)T_LEN*N2*sizeof(float), stream);
    hipMemsetAsync(Hh,  0x7F, (size_t)T_LEN*512*sizeof(float), stream);

    fused_gemm_lstm<<<NLSTM + 2048, 1024, 0, stream>>>(
        sentence, embed, Wihf, Wihb, bihf, bhhf, bihb, bhhb,
        Whhf, Whhb, h0, c0, gin, Hh);
    feats_kernel<<<T_LEN/16, 192, 0, stream>>>(Hh, Wtag, btag, feats);
    viterbi_kernel<<<1, 256, 0, stream>>>(feats, trans, out);
}

// Round 14
// 6814.926 us; speedup vs baseline: 1.4347x; 1.0759x over previous
//
#include <hip/hip_runtime.h>

#define T_LEN 4096
#define EMB   300
#define HD    256
#define G4    1024      // 4*HD (gate rows per direction)
#define N2    2048      // both directions
#define TAGS  12
#define NEGV  -10000.0f
#define SENT  0x7F7F7F7Fu   // memset byte 0x7F -> 3.396e38f; real values never reach it
#define NLSTM 29            // lstm sub-grid (8 workers + XCD spacers)
#define VCH   512           // viterbi feats chunk (24 KB LDS)

// ---------------------------------------------------------------------------
// Fused kernel: blocks 0..28 = persistent BiLSTM (r10 structure); blocks
// 29.. = the gin GEMM running concurrently (sentinel-polled handoff).
// ---------------------------------------------------------------------------
#define MV(K) { const float4 hv = h4[K];                    \
    a0 = fmaf(wA##K.x, hv.x, a0);                           \
    a1 = fmaf(wA##K.y, hv.y, a1);                           \
    a2 = fmaf(wA##K.z, hv.z, a2);                           \
    a3 = fmaf(wA##K.w, hv.w, a3); }

__global__ __launch_bounds__(1024) void fused_gemm_lstm(
    const int* __restrict__ sent, const float* __restrict__ embed,
    const float* __restrict__ Wihf, const float* __restrict__ Wihb,
    const float* __restrict__ bihf, const float* __restrict__ bhhf,
    const float* __restrict__ bihb, const float* __restrict__ bhhb,
    const float* Whh_f, const float* Whh_b,            // NOT restrict (anti-remat)
    const float* __restrict__ h0, const float* __restrict__ c0,
    float* gin,                      // [T][2048], 0x7F-filled; gemm writes, lstm polls
    float* Hh)                       // [T][512],  0x7F-filled; h exchange + history
{
    __shared__ __align__(16) char smem[145*1024];
    const int blk = blockIdx.x;
    const int tid = threadIdx.x;

    if (blk >= NLSTM) {
        // ================= GEMM path =================
        float* AsT  = (float*)smem;              // [32][68]
        float* BsT  = (float*)(smem + 8704);     // [32][68]
        int*   sIdx = (int*)  (smem + 17408);    // [64]
        const int g  = blk - NLSTM;
        const int kk8 = g >> 5;                  // 0..63
        const int bn  = g & 31;
        const int bm  = (kk8 & 1) ? (63 - (kk8 >> 1)) : (kk8 >> 1);  // middle-out

        if (tid < 64) sIdx[tid] = sent[bm*64 + tid];
        __syncthreads();

        const int srow = tid >> 4;               // 0..63
        const int skj  = (tid & 15) << 1;        // 0,2,..,30
        const int m0   = (tid >> 5) << 1;        // 0..62 (row pair)
        const int n0   = (tid & 31) << 1;        // 0..62 (col pair)
        const int rn   = bn * 64;
        float acc00=0.f, acc01=0.f, acc10=0.f, acc11=0.f;

        for (int kc = 0; kc < 10; ++kc) {        // K chunks of 32 (guard 300)
            const int k0 = kc*32 + skj;
            float2 va = make_float2(0.f, 0.f), vb = make_float2(0.f, 0.f);
            if (k0 + 1 < EMB) {                  // EMB even: float2 all-or-nothing
                va = *(const float2*)(embed + (long)sIdx[srow]*EMB + k0);
                const int r = rn + srow;
                const float* bsrc = (r < G4) ? (Wihf + (long)r*EMB)
                                             : (Wihb + (long)(r-G4)*EMB);
                vb = *(const float2*)(bsrc + k0);
            }
            AsT[skj*68 + srow]     = va.x;
            AsT[(skj+1)*68 + srow] = va.y;
            BsT[skj*68 + srow]     = vb.x;
            BsT[(skj+1)*68 + srow] = vb.y;
            __syncthreads();
            #pragma unroll
            for (int kk = 0; kk < 32; ++kk) {
                const float2 a2v = *(const float2*)&AsT[kk*68 + m0];
                const float2 b2v = *(const float2*)&BsT[kk*68 + n0];
                acc00 = fmaf(a2v.x, b2v.x, acc00);
                acc01 = fmaf(a2v.x, b2v.y, acc01);
                acc10 = fmaf(a2v.y, b2v.x, acc10);
                acc11 = fmaf(a2v.y, b2v.y, acc11);
            }
            __syncthreads();
        }

        const int c0i = rn + n0, c1i = c0i + 1;
        const float bias0 = (c0i < G4) ? (bihf[c0i] + bhhf[c0i])
                                       : (bihb[c0i-G4] + bhhb[c0i-G4]);
        const float bias1 = (c1i < G4) ? (bihf[c1i] + bhhf[c1i])
                                       : (bihb[c1i-G4] + bhhb[c1i-G4]);
        const long t0 = (long)(bm*64 + m0), t1 = t0 + 1;
        __hip_atomic_store(&gin[t0*N2 + c0i], acc00 + bias0,
                           __ATOMIC_RELAXED, __HIP_MEMORY_SCOPE_AGENT);
        __hip_atomic_store(&gin[t0*N2 + c1i], acc01 + bias1,
                           __ATOMIC_RELAXED, __HIP_MEMORY_SCOPE_AGENT);
        __hip_atomic_store(&gin[t1*N2 + c0i], acc10 + bias0,
                           __ATOMIC_RELAXED, __HIP_MEMORY_SCOPE_AGENT);
        __hip_atomic_store(&gin[t1*N2 + c1i], acc11 + bias1,
                           __ATOMIC_RELAXED, __HIP_MEMORY_SCOPE_AGENT);
        return;
    }

    // ================= LSTM path (r10 structure) =================
    const int m8 = blk & 7;
    if (m8 != 0 && m8 != 4) return;     // XCD placement spacers
    const int dir = (m8 == 4);
    const int b   = blk >> 3;           // unit-slice 0..3
    const int u     = tid & 63;
    const int wvid  = tid >> 6;         // 0..15
    const int gate  = wvid >> 2;        // wave-uniform
    const int q     = wvid & 3;         // wave-uniform quarter
    const int unit0 = b*64;
    const int row   = gate*64 + u;            // block-local row 0..255
    const int grow  = gate*HD + unit0 + u;    // gate row 0..1023

    float* hS  = (float*)smem;            // 256 floats
    float* ps  = (float*)(smem + 1024);   // [3][256]
    float* gvS = (float*)(smem + 4096);   // 256 floats

    // --- 64 weights as named SSA float4 ---
    const float4* W4 = (const float4*)((dir ? Whh_b : Whh_f)
                                       + (long)grow*HD + q*64);
    const float4 wA0  = W4[0],  wA1  = W4[1],  wA2  = W4[2],  wA3  = W4[3];
    const float4 wA4  = W4[4],  wA5  = W4[5],  wA6  = W4[6],  wA7  = W4[7];
    const float4 wA8  = W4[8],  wA9  = W4[9],  wA10 = W4[10], wA11 = W4[11];
    const float4 wA12 = W4[12], wA13 = W4[13], wA14 = W4[14], wA15 = W4[15];

    float cst = 0.f;
    if (tid < 64) cst = c0[dir*HD + unit0 + tid];       // owners: wave 0
    if (tid < HD) hS[tid] = h0[dir*HD + tid];

    float* ginD = gin + dir*G4;
    float gx;
    {   // initial gin word: cold poll
        const long gi0 = (long)(dir ? T_LEN-1 : 0)*N2 + grow;
        do {
            gx = __hip_atomic_load(&ginD[gi0], __ATOMIC_RELAXED,
                                   __HIP_MEMORY_SCOPE_AGENT);
        } while (__float_as_uint(gx) == SENT);
    }

    #pragma unroll 1
    for (int s = 0; s < T_LEN; ++s) {
        const int t = dir ? (T_LEN-1-s) : s;
        float gxn = 0.f;
        long  gidx = 0;
        if (s+1 < T_LEN) {                     // issue next-step gin load EARLY
            gidx = (long)(dir ? t-1 : t+1)*N2 + grow;
            gxn = __hip_atomic_load(&ginD[gidx], __ATOMIC_RELAXED,
                                    __HIP_MEMORY_SCOPE_AGENT);
            __builtin_amdgcn_sched_barrier(0); // pin the early issue
        }

        __syncthreads();                       // (A) hS(s) complete
        const float4* h4 = (const float4*)(hS + q*64);   // uniform-addr broadcast
        float a0=0.f, a1=0.f, a2=0.f, a3=0.f;
        MV(0)  MV(1)  MV(2)  MV(3)
        MV(4)  MV(5)  MV(6)  MV(7)
        MV(8)  MV(9)  MV(10) MV(11)
        MV(12) MV(13) MV(14) MV(15)
        const float a = (a0+a1)+(a2+a3);
        if (q != 0) ps[(q-1)*256 + row] = a;
        __syncthreads();                       // (B) partials ready

        if (q == 0) {                          // waves 0,4,8,12: finalize + activate
            const float raw = a + ps[row] + ps[256+row] + ps[512+row] + gx;
            gvS[row] = (gate == 2) ? tanhf(raw) : 1.f/(1.f + expf(-raw));
        }
        __syncthreads();                       // (C) gvS ready

        if (tid < 64) {                        // wave 0 = owners: c/h update + publish
            const float i_ = gvS[tid],       f_ = gvS[64+tid];
            const float g_ = gvS[128+tid],   o_ = gvS[192+tid];
            cst = fmaf(f_, cst, i_*g_);
            const float hv = o_ * tanhf(cst);
            hS[unit0 + tid] = hv;              // own slice: LDS only
            __hip_atomic_store(&Hh[(long)t*512 + dir*HD + unit0 + tid], hv,
                               __ATOMIC_RELAXED, __HIP_MEMORY_SCOPE_AGENT);
        } else if (tid < 256 && s+1 < T_LEN) { // waves 1-3: poll one foreign word each
            const int fidx = tid - 64;                      // 0..191
            const int gu   = (fidx < unit0) ? fidx : fidx + 64;
            const long idx = (long)t*512 + dir*HD + gu;
            float v;
            do {
                v = __hip_atomic_load(&Hh[idx], __ATOMIC_RELAXED,
                                      __HIP_MEMORY_SCOPE_AGENT);
            } while (__float_as_uint(v) == SENT);
            hS[gu] = v;
        }

        if (s+1 < T_LEN) {                     // check-late: usually already ready
            while (__float_as_uint(gxn) == SENT)
                gxn = __hip_atomic_load(&ginD[gidx], __ATOMIC_RELAXED,
                                        __HIP_MEMORY_SCOPE_AGENT);
        }
        gx = gxn;
    }
}

// ---------------------------------------------------------------------------
// Kernel 3: feats[t][tag] = [hf|hb][t] . W_tag[tag] + b_tag
// ---------------------------------------------------------------------------
__global__ __launch_bounds__(192) void feats_kernel(
    const float* __restrict__ Hhist, const float* __restrict__ Wtag,
    const float* __restrict__ btag, float* __restrict__ feats)
{
    __shared__ __align__(16) float Ws[TAGS][512];
    const int tid = threadIdx.x;
    for (int i = tid; i < TAGS*512; i += 192) Ws[0][i] = Wtag[i];
    __syncthreads();
    const int tl = tid / TAGS;            // 0..15
    const int tg = tid % TAGS;
    const int t  = blockIdx.x * 16 + tl;
    const float4* hrow = (const float4*)(Hhist + (long)t*512);
    const float4* wrow = (const float4*)(&Ws[tg][0]);
    float a0=0.f,a1=0.f,a2=0.f,a3=0.f;
    #pragma unroll 8
    for (int k = 0; k < 128; ++k) {
        const float4 h = hrow[k];
        const float4 ww = wrow[k];
        a0=fmaf(h.x,ww.x,a0); a1=fmaf(h.y,ww.y,a1);
        a2=fmaf(h.z,ww.z,a2); a3=fmaf(h.w,ww.w,a3);
    }
    feats[t*TAGS + tg] = ((a0+a1)+(a2+a3)) + btag[tg];
}

// ---------------------------------------------------------------------------
// Kernel 4: Viterbi — 3-phase, single wave of 64 lanes.
// Phase 1 (forward): fv vector REPLICATED in every lane's registers; per
//   step: 12 adds + fmaxf tree (no argmax, no shfl), publish via fvS[lane],
//   read back as 3 uniform ds_read_b128. fv_pre[t] streamed to global.
// Phase 2 (parallel bp recovery): bp[t][to] = argmax_f(fv_pre[t][f]+tr[to][f])
//   — 49152 independent argmaxes across 64 lanes, sequential strict-> per
//   list (np first-max semantics), into 48 KB LDS.
// Phase 3: serial backtrack from LDS bps.
// Replaces the old 12-sequential-shfl inner loop (~1 ms -> ~0.3 ms).
// ---------------------------------------------------------------------------
__global__ __launch_bounds__(64) void viterbi_kernel(
    const float* __restrict__ feats, const float* __restrict__ trans,
    float* __restrict__ fvstore, float* __restrict__ out)
{
    __shared__ __align__(16) float fS[VCH*TAGS];        // 24 KB feats chunk
    __shared__ __align__(16) float fvS[16];
    __shared__ __align__(16) float trS[TAGS*TAGS];
    __shared__ unsigned char bps[T_LEN*TAGS];           // 48 KB backpointers
    const int lane = threadIdx.x;

    for (int i = lane; i < TAGS*TAGS; i += 64) trS[i] = trans[i];

    // this lane's transition row (valid for lane < TAGS; others unused)
    const int trow = (lane < TAGS) ? lane : 0;
    float tr[TAGS];
    #pragma unroll
    for (int f = 0; f < TAGS; ++f) tr[f] = trans[trow*TAGS + f];

    // fv replicated in all lanes
    float fvv[TAGS];
    #pragma unroll
    for (int f = 0; f < TAGS; ++f) fvv[f] = (f == 10) ? 0.f : NEGV;  // START=10

    // ---------------- Phase 1: forward max-scan ----------------
    for (int c = 0; c < T_LEN/VCH; ++c) {
        __syncthreads();
        {   // stage feats chunk (coalesced float4)
            const float4* src = (const float4*)(feats + (long)c*VCH*TAGS);
            float4* dst = (float4*)fS;
            #pragma unroll 4
            for (int i = lane; i < VCH*TAGS/4; i += 64) dst[i] = src[i];
        }
        __syncthreads();
        for (int s = 0; s < VCH; ++s) {
            const int t = c*VCH + s;
            if (lane < TAGS) {
                fvstore[(long)t*TAGS + lane] = fvv[lane];   // fv_pre (fire&forget)
                float cand[TAGS];
                #pragma unroll
                for (int f = 0; f < TAGS; ++f) cand[f] = fvv[f] + tr[f];
                const float m =
                    fmaxf(fmaxf(fmaxf(fmaxf(cand[0],cand[1]), fmaxf(cand[2],cand[3])),
                                fmaxf(fmaxf(cand[4],cand[5]), fmaxf(cand[6],cand[7]))),
                          fmaxf(fmaxf(cand[8],cand[9]), fmaxf(cand[10],cand[11])));
                fvS[lane] = m + fS[s*TAGS + lane];
            }
            __syncthreads();                    // single wave: cheap
            const float4 A = *(const float4*)&fvS[0];
            const float4 B = *(const float4*)&fvS[4];
            const float4 C = *(const float4*)&fvS[8];
            fvv[0]=A.x; fvv[1]=A.y; fvv[2]=A.z; fvv[3]=A.w;
            fvv[4]=B.x; fvv[5]=B.y; fvv[6]=B.z; fvv[7]=B.w;
            fvv[8]=C.x; fvv[9]=C.y; fvv[10]=C.z; fvv[11]=C.w;
            __syncthreads();                    // reads done before next write
        }
    }

    // ---------------- Phase 2: parallel backpointer recovery ----------------
    __syncthreads();
    for (int idx = lane; idx < T_LEN*TAGS; idx += 64) {
        const int t  = idx / TAGS;
        const int to = idx - t*TAGS;
        const float* fp = fvstore + (long)t*TAGS;
        float best = -3.4e38f; int bp = 0;
        #pragma unroll
        for (int f = 0; f < TAGS; ++f) {
            const float v = fp[f] + trS[to*TAGS + f];
            if (v > best) { best = v; bp = f; }   // strict > = np first-max
        }
        bps[idx] = (unsigned char)bp;
    }
    __syncthreads();

    // ---------------- Phase 3: terminal + serial backtrack ----------------
    if (lane == 0) {
        float bestv = -3.4e38f; int best = 0;
        #pragma unroll
        for (int g = 0; g < TAGS; ++g) {
            const float v = fvv[g] + trS[11*TAGS + g];    // STOP = 11
            if (v > bestv) { bestv = v; best = g; }
        }
        out[0] = bestv;
        int cur = best;
        for (int t = T_LEN-1; t >= 0; --t) {
            out[1+t] = (float)cur;
            cur = bps[t*TAGS + cur];
        }
    }
}

// ---------------------------------------------------------------------------
// Host launch.  ws layout (floats):
//   gin     [4096*2048] = 33.5 MB  (0x7F sentinel-filled each launch)
//   Hh      [4096*512]  =  8.4 MB  (0x7F sentinel-filled each launch)
//   feats   [4096*12]   =  0.2 MB
//   fvstore [4096*12]   =  0.2 MB
// ---------------------------------------------------------------------------
extern "C" void kernel_launch(void* const* d_in, const int* in_sizes, int n_in,
                              void* d_out, int out_size, void* d_ws, size_t ws_size,
                              hipStream_t stream)
{
    (void)in_sizes; (void)n_in; (void)out_size; (void)ws_size;
    const int*   sentence = (const int*)  d_in[0];
    const float* h0       = (const float*)d_in[1];
    const float* c0       = (const float*)d_in[2];
    const float* embed    = (const float*)d_in[3];
    const float* Wihf     = (const float*)d_in[4];
    const float* Whhf     = (const float*)d_in[5];
    const float* bihf     = (const float*)d_in[6];
    const float* bhhf     = (const float*)d_in[7];
    const float* Wihb     = (const float*)d_in[8];
    const float* Whhb     = (const float*)d_in[9];
    const float* bihb     = (const float*)d_in[10];
    const float* bhhb     = (const float*)d_in[11];
    const float* Wtag     = (const float*)d_in[12];
    const float* btag     = (const float*)d_in[13];
    const float* trans    = (const float*)d_in[14];
    float* out = (float*)d_out;

    float* gin     = (float*)d_ws;
    float* Hh      = gin   + (long)T_LEN*N2;
    float* feats   = Hh    + (long)T_LEN*512;
    float* fvstore = feats + (long)T_LEN*TAGS;

    hipMemsetAsync(gin, 0x7F, (size_t)T_LEN*N2*sizeof(float), stream);
    hipMemsetAsync(Hh,  0x7F, (size_t)T_LEN*512*sizeof(float), stream);

    fused_gemm_lstm<<<NLSTM + 2048, 1024, 0, stream>>>(
        sentence, embed, Wihf, Wihb, bihf, bhhf, bihb, bhhb,
        Whhf, Whhb, h0, c0, gin, Hh);
    feats_kernel<<<T_LEN/16, 192, 0, stream>>>(Hh, Wtag, btag, feats);
    viterbi_kernel<<<1, 64, 0, stream>>>(feats, trans, fvstore, out);
}